// Round 1
// baseline (324.330 us; speedup 1.0000x reference)
//
#include <hip/hip_runtime.h>

// Shapes (fixed by the reference):
//   x:  (N=32, C=384, H=56, W=56)  -> (n, c, p) with HW=3136
//   gf: (N=32, M=8, D=768)
//   W_kv: (E=768, D=768), b_kv: (768,)
//   kv[n][m][e] = clip(sum_d gf[n][m][d]*W[e][d] + b[e], 0, 6)
//   K = kv[..., :384], V = kv[..., 384:]
//   scores[n,p,k] = sum_c x[n,c,p]*K[n,k,c]; attn = softmax_k
//   out[n,c,p] = x[n,c,p] + sum_k attn[n,p,k]*V[n,k,c]

#define NC 384
#define HWP 3136
#define DD 768
#define MM 8
#define EE 768

// ---------------- Kernel 1: KV projection + ReLU6 ----------------
// grid (6, 32), block 256. Each block: one n, 128 e's, all 8 m's.
__global__ __launch_bounds__(256) void kv_kernel(const float* __restrict__ gf,
                                                 const float* __restrict__ Wk,
                                                 const float* __restrict__ bk,
                                                 float* __restrict__ kv) {
    __shared__ float g[MM * DD];  // 24 KB, this n's global_feature rows
    const int n = blockIdx.y;
    const int et = blockIdx.x;   // 0..5
    const int t = threadIdx.x;

    const float* gfn = gf + (size_t)n * (MM * DD);
    for (int i = t; i < MM * DD; i += 256) g[i] = gfn[i];
    __syncthreads();

    const int e = et * 128 + (t & 127);
    const int mb = (t >> 7) * 4;  // wave-uniform: m group 0..3 or 4..7

    const float4* w4 = (const float4*)(Wk + (size_t)e * DD);
    const float4* g0 = (const float4*)(g + (mb + 0) * DD);
    const float4* g1 = (const float4*)(g + (mb + 1) * DD);
    const float4* g2 = (const float4*)(g + (mb + 2) * DD);
    const float4* g3 = (const float4*)(g + (mb + 3) * DD);

    float a0 = 0.f, a1 = 0.f, a2 = 0.f, a3 = 0.f;
    #pragma unroll 8
    for (int i = 0; i < DD / 4; ++i) {
        const float4 w = w4[i];
        const float4 v0 = g0[i];
        const float4 v1 = g1[i];
        const float4 v2 = g2[i];
        const float4 v3 = g3[i];
        a0 += w.x * v0.x + w.y * v0.y + w.z * v0.z + w.w * v0.w;
        a1 += w.x * v1.x + w.y * v1.y + w.z * v1.z + w.w * v1.w;
        a2 += w.x * v2.x + w.y * v2.y + w.z * v2.z + w.w * v2.w;
        a3 += w.x * v3.x + w.y * v3.y + w.z * v3.z + w.w * v3.w;
    }
    const float bv = bk[e];
    float* o = kv + (size_t)n * (MM * EE);
    o[(mb + 0) * EE + e] = fminf(fmaxf(a0 + bv, 0.f), 6.f);
    o[(mb + 1) * EE + e] = fminf(fmaxf(a1 + bv, 0.f), 6.f);
    o[(mb + 2) * EE + e] = fminf(fmaxf(a2 + bv, 0.f), 6.f);
    o[(mb + 3) * EE + e] = fminf(fmaxf(a3 + bv, 0.f), 6.f);
}

// ---------------- Kernel 2: fused attention + residual ----------------
// grid (49, 32), block 256. Block = (n, 64 spatial positions).
// lane = position (coalesced 256B/wave global access), wave = 96-channel chunk.
// x kept in 96 VGPRs per thread: read from HBM exactly once.
__global__ __launch_bounds__(256) void attn_kernel(const float* __restrict__ x,
                                                   const float* __restrict__ kv,
                                                   float* __restrict__ out) {
    __shared__ float kvs[MM * EE];      // 24 KB: [k][0..383]=K, [k][384..767]=V
    __shared__ float sc[8][4][64];      // 8 KB: partial scores [k][chunk][p]
    __shared__ float attn_s[8][64];     // 2 KB

    const int n = blockIdx.y;
    const int tile = blockIdx.x;        // 0..48
    const int t = threadIdx.x;
    const int p = t & 63;               // lane = position
    const int chunk = t >> 6;           // wave = channel chunk (0..3)
    const int pos = tile * 64 + p;
    const int c0 = chunk * 96;

    // stage this n's K and V (coalesced, small)
    const float* kvn = kv + (size_t)n * (MM * EE);
    for (int i = t; i < MM * EE; i += 256) kvs[i] = kvn[i];

    // load my 96 x values into registers (one HBM read of x, coalesced)
    const float* xp = x + (size_t)n * NC * HWP + (size_t)c0 * HWP + pos;
    float xr[96];
    #pragma unroll
    for (int i = 0; i < 96; ++i) xr[i] = xp[(size_t)i * HWP];

    __syncthreads();

    // partial scores over my channel chunk; K via LDS float4 broadcast
    float acc[8];
    #pragma unroll
    for (int k = 0; k < 8; ++k) acc[k] = 0.f;
    #pragma unroll
    for (int i = 0; i < 96; i += 4) {
        #pragma unroll
        for (int k = 0; k < 8; ++k) {
            const float4 kk = *(const float4*)&kvs[k * EE + c0 + i];
            acc[k] += xr[i] * kk.x + xr[i + 1] * kk.y + xr[i + 2] * kk.z + xr[i + 3] * kk.w;
        }
    }
    #pragma unroll
    for (int k = 0; k < 8; ++k) sc[k][chunk][p] = acc[k];  // stride-1 in p: conflict-free
    __syncthreads();

    // softmax over the 8 keys, one position per thread (wave 0)
    if (t < 64) {
        float s[8];
        float mx = -1e30f;
        #pragma unroll
        for (int k = 0; k < 8; ++k) {
            s[k] = sc[k][0][t] + sc[k][1][t] + sc[k][2][t] + sc[k][3][t];
            mx = fmaxf(mx, s[k]);
        }
        float sum = 0.f;
        #pragma unroll
        for (int k = 0; k < 8; ++k) {
            s[k] = __expf(s[k] - mx);
            sum += s[k];
        }
        const float inv = 1.f / sum;
        #pragma unroll
        for (int k = 0; k < 8; ++k) attn_s[k][t] = s[k] * inv;
    }
    __syncthreads();

    float aw[8];
    #pragma unroll
    for (int k = 0; k < 8; ++k) aw[k] = attn_s[k][p];

    // output: out[n,c,p] = x + sum_k aw[k]*V[k][c]; V via LDS float4 broadcast
    float* op = out + (size_t)n * NC * HWP + (size_t)c0 * HWP + pos;
    #pragma unroll
    for (int i = 0; i < 96; i += 4) {
        float o0 = xr[i], o1 = xr[i + 1], o2 = xr[i + 2], o3 = xr[i + 3];
        #pragma unroll
        for (int k = 0; k < 8; ++k) {
            const float4 vv = *(const float4*)&kvs[k * EE + 384 + c0 + i];
            o0 += aw[k] * vv.x;
            o1 += aw[k] * vv.y;
            o2 += aw[k] * vv.z;
            o3 += aw[k] * vv.w;
        }
        op[(size_t)(i + 0) * HWP] = o0;
        op[(size_t)(i + 1) * HWP] = o1;
        op[(size_t)(i + 2) * HWP] = o2;
        op[(size_t)(i + 3) * HWP] = o3;
    }
}

extern "C" void kernel_launch(void* const* d_in, const int* in_sizes, int n_in,
                              void* d_out, int out_size, void* d_ws, size_t ws_size,
                              hipStream_t stream) {
    const float* x  = (const float*)d_in[0];
    const float* gf = (const float*)d_in[1];
    const float* Wk = (const float*)d_in[2];
    const float* bk = (const float*)d_in[3];
    float* out = (float*)d_out;
    float* kv = (float*)d_ws;  // 32*8*768 floats = 768 KB

    kv_kernel<<<dim3(6, 32), 256, 0, stream>>>(gf, Wk, bk, kv);
    attn_kernel<<<dim3(49, 32), 256, 0, stream>>>(x, kv, out);
}

// Round 2
// 321.625 us; speedup vs baseline: 1.0084x; 1.0084x over previous
//
#include <hip/hip_runtime.h>

// Shapes (fixed by the reference):
//   x:  (N=32, C=384, H=56, W=56)  -> (n, c, p) with HW=3136
//   gf: (N=32, M=8, D=768)
//   W_kv: (E=768, D=768), b_kv: (768,)
//   kv[n][m][e] = clip(sum_d gf[n][m][d]*W[e][d] + b[e], 0, 6)
//   K = kv[..., :384], V = kv[..., 384:]
//   scores[n,p,k] = sum_c x[n,c,p]*K[n,k,c]; attn = softmax_k
//   out[n,c,p] = x[n,c,p] + sum_k attn[n,p,k]*V[n,k,c]

#define NC 384
#define HWP 3136
#define DD 768
#define MM 8
#define EE 768

// ---------------- Kernel 1: KV projection + ReLU6 ----------------
// grid (12, 32), block 256. Block = one n, 64 e's, all 8 m's (2 m's/thread).
__global__ __launch_bounds__(256) void kv_kernel(const float* __restrict__ gf,
                                                 const float* __restrict__ Wk,
                                                 const float* __restrict__ bk,
                                                 float* __restrict__ kv) {
    __shared__ float g[MM * DD];  // 24 KB, this n's global_feature rows
    const int n = blockIdx.y;
    const int et = blockIdx.x;   // 0..11
    const int t = threadIdx.x;

    const float* gfn = gf + (size_t)n * (MM * DD);
    for (int i = t; i < MM * DD; i += 256) g[i] = gfn[i];
    __syncthreads();

    const int e = et * 64 + (t & 63);
    const int mb = (t >> 6) * 2;  // wave-uniform m pair

    const float4* w4 = (const float4*)(Wk + (size_t)e * DD);
    const float4* g0 = (const float4*)(g + (mb + 0) * DD);
    const float4* g1 = (const float4*)(g + (mb + 1) * DD);

    float a0 = 0.f, a1 = 0.f;
    #pragma unroll 8
    for (int i = 0; i < DD / 4; ++i) {
        const float4 w = w4[i];
        const float4 v0 = g0[i];
        const float4 v1 = g1[i];
        a0 += w.x * v0.x + w.y * v0.y + w.z * v0.z + w.w * v0.w;
        a1 += w.x * v1.x + w.y * v1.y + w.z * v1.z + w.w * v1.w;
    }
    const float bv = bk[e];
    float* o = kv + (size_t)n * (MM * EE);
    o[(mb + 0) * EE + e] = fminf(fmaxf(a0 + bv, 0.f), 6.f);
    o[(mb + 1) * EE + e] = fminf(fmaxf(a1 + bv, 0.f), 6.f);
}

// ---------------- Kernel 2: fused attention + residual ----------------
// grid (49, 32), block 256. Block = (n, 64 spatial positions).
// Thread = (p4 = t&15: quad of 4 consecutive positions -> float4 global access,
//           g  = t>>4: 24-channel group). All x loads/stores are 16 B/lane.
// Score reduction over the wave's 4 channel-groups via shfl_xor (no LDS).
__global__ __launch_bounds__(256) void attn_kernel(const float* __restrict__ x,
                                                   const float* __restrict__ kv,
                                                   float* __restrict__ out) {
    __shared__ float kvs[MM * EE];      // 24 KB: [k][0..383]=K, [k][384..767]=V
    __shared__ float sc[4][8][64];      // 8 KB: per-wave scores [w][k][p]
    __shared__ float attn_s[8][64];     // 2 KB

    const int n = blockIdx.y;
    const int tile = blockIdx.x;        // 0..48
    const int t = threadIdx.x;
    const int p4 = t & 15;              // position quad within the 64-pos tile
    const int g = t >> 4;               // channel group (0..15), 24 ch each
    const int w = t >> 6;               // wave
    const int pos0 = tile * 64 + p4 * 4;
    const int c0 = g * 24;

    // stage this n's K and V (coalesced float4, small)
    const float4* kvn4 = (const float4*)(kv + (size_t)n * (MM * EE));
    float4* kvs4 = (float4*)kvs;
    for (int i = t; i < MM * EE / 4; i += 256) kvs4[i] = kvn4[i];

    // load my 24 channels x 4 positions of x (float4, 16B/lane, coalesced)
    const float* xp = x + (size_t)n * NC * HWP + (size_t)c0 * HWP + pos0;
    float4 xr[24];
    #pragma unroll
    for (int i = 0; i < 24; ++i) xr[i] = *(const float4*)(xp + (size_t)i * HWP);

    __syncthreads();

    // partial scores over my 24 channels, 4 positions, 8 keys
    float acc[8][4];
    #pragma unroll
    for (int k = 0; k < 8; ++k)
        #pragma unroll
        for (int j = 0; j < 4; ++j) acc[k][j] = 0.f;

    #pragma unroll
    for (int i = 0; i < 24; ++i) {
        const float4 xv = xr[i];
        #pragma unroll
        for (int k = 0; k < 8; ++k) {
            const float kc = kvs[k * EE + c0 + i];
            acc[k][0] += xv.x * kc;
            acc[k][1] += xv.y * kc;
            acc[k][2] += xv.z * kc;
            acc[k][3] += xv.w * kc;
        }
    }

    // reduce across the wave's 4 channel-groups (lanes l, l^16, l^32 share p4)
    #pragma unroll
    for (int k = 0; k < 8; ++k) {
        #pragma unroll
        for (int j = 0; j < 4; ++j) {
            acc[k][j] += __shfl_xor(acc[k][j], 16, 64);
            acc[k][j] += __shfl_xor(acc[k][j], 32, 64);
        }
    }
    if ((t & 48) == 0) {  // lanes 0..15 of each wave
        #pragma unroll
        for (int k = 0; k < 8; ++k) {
            *(float4*)&sc[w][k][p4 * 4] =
                make_float4(acc[k][0], acc[k][1], acc[k][2], acc[k][3]);
        }
    }
    __syncthreads();

    // softmax over the 8 keys, one position per thread (wave 0)
    if (t < 64) {
        float s[8];
        float mx = -1e30f;
        #pragma unroll
        for (int k = 0; k < 8; ++k) {
            s[k] = sc[0][k][t] + sc[1][k][t] + sc[2][k][t] + sc[3][k][t];
            mx = fmaxf(mx, s[k]);
        }
        float sum = 0.f;
        #pragma unroll
        for (int k = 0; k < 8; ++k) {
            s[k] = __expf(s[k] - mx);
            sum += s[k];
        }
        const float inv = 1.f / sum;
        #pragma unroll
        for (int k = 0; k < 8; ++k) attn_s[k][t] = s[k] * inv;
    }
    __syncthreads();

    // attention weights for my 4 positions (float4 LDS read, broadcast groups)
    float4 aw[8];
    #pragma unroll
    for (int k = 0; k < 8; ++k) aw[k] = *(const float4*)&attn_s[k][p4 * 4];

    // output: out = x + sum_k aw[k]*V[k][c], float4 stores
    float* op = out + (size_t)n * NC * HWP + (size_t)c0 * HWP + pos0;
    #pragma unroll
    for (int i = 0; i < 24; ++i) {
        float4 o = xr[i];
        #pragma unroll
        for (int k = 0; k < 8; ++k) {
            const float v = kvs[k * EE + 384 + c0 + i];
            o.x += aw[k].x * v;
            o.y += aw[k].y * v;
            o.z += aw[k].z * v;
            o.w += aw[k].w * v;
        }
        *(float4*)(op + (size_t)i * HWP) = o;
    }
}

extern "C" void kernel_launch(void* const* d_in, const int* in_sizes, int n_in,
                              void* d_out, int out_size, void* d_ws, size_t ws_size,
                              hipStream_t stream) {
    const float* x  = (const float*)d_in[0];
    const float* gf = (const float*)d_in[1];
    const float* Wk = (const float*)d_in[2];
    const float* bk = (const float*)d_in[3];
    float* out = (float*)d_out;
    float* kv = (float*)d_ws;  // 32*8*768 floats = 768 KB

    kv_kernel<<<dim3(12, 32), 256, 0, stream>>>(gf, Wk, bk, kv);
    attn_kernel<<<dim3(49, 32), 256, 0, stream>>>(x, kv, out);
}